// Round 1
// 470.734 us; speedup vs baseline: 1.2263x; 1.2263x over previous
//
#include <hip/hip_runtime.h>

#define Tt 128
#define Nn 2048
#define Hh 128
#define Dd 128
#define NB 8          // batch rows per block
#define LDA 136       // bf16 LDS row stride (shorts): 128 + 8 pad
#define LDG 388       // fp32 LDS row stride (dwords): 384 + 4 pad

// workspace layout (floats)
#define WC_OFF  0            // Wc  = Wih@W2@W1   (384 x 128)
#define BC_OFF  49152        // bc  = Wih@(W2@b1+b2)+bih  (384)
#define TMP_OFF 49536        // Tmp = W2@W1       (128 x 128)
#define BT_OFF  65920        // bt  = W2@b1+b2    (128)

typedef __attribute__((ext_vector_type(8))) short v8s;
typedef __attribute__((ext_vector_type(4))) float v4f;
typedef __attribute__((ext_vector_type(2))) float v2f;

__device__ __forceinline__ unsigned short f2bf(float f) {
    unsigned int u = __builtin_bit_cast(unsigned int, f);
    u += 0x7FFFu + ((u >> 16) & 1u);   // round-to-nearest-even
    return (unsigned short)(u >> 16);
}

__device__ __forceinline__ v4f mfma_bf(v8s a, v8s b, v4f c) {
    return __builtin_amdgcn_mfma_f32_16x16x32_bf16(a, b, c, 0, 0, 0);
}

__device__ __forceinline__ v8s load_wfrag_bf(const float* __restrict__ W, int row, int k0) {
    const v4f* p = (const v4f*)(W + row * 128 + k0);
    v4f a = p[0], b = p[1];
    v8s r;
    r[0] = (short)f2bf(a[0]); r[1] = (short)f2bf(a[1]);
    r[2] = (short)f2bf(a[2]); r[3] = (short)f2bf(a[3]);
    r[4] = (short)f2bf(b[0]); r[5] = (short)f2bf(b[1]);
    r[6] = (short)f2bf(b[2]); r[7] = (short)f2bf(b[3]);
    return r;
}

__device__ __forceinline__ float sigm(float x) { return __frcp_rn(1.f + __expf(-x)); }
__device__ __forceinline__ float tanh_f(float x) {
    return 2.f * __frcp_rn(1.f + __expf(-2.f * x)) - 1.f;
}

// Raw barrier: drain own LDS ops (producer visibility + consumer WAR safety),
// but do NOT drain vmcnt -> out-stores / x-prefetch stay in flight across steps.
// Single asm with memory clobber: no memory op can be scheduled across it.
#define BARRIER() asm volatile("s_waitcnt lgkmcnt(0)\n\ts_barrier" ::: "memory")

// ---------- prep: compose the affine MLP into one weight matrix ----------
__global__ void prep_tmp(const float* __restrict__ W1, const float* __restrict__ b1,
                         const float* __restrict__ W2, const float* __restrict__ b2,
                         float* __restrict__ ws) {
    float* Tmp = ws + TMP_OFF;
    float* bt  = ws + BT_OFF;
    int j = blockIdx.x, d = threadIdx.x;
    float acc = 0.f;
    for (int k = 0; k < 128; ++k) acc += W2[j * 128 + k] * W1[k * 128 + d];
    Tmp[j * 128 + d] = acc;
    if (d == 0) {
        float s = 0.f;
        for (int k = 0; k < 128; ++k) s += W2[j * 128 + k] * b1[k];
        bt[j] = s + b2[j];
    }
}

__global__ void prep_wc(const float* __restrict__ Wih, const float* __restrict__ bih,
                        float* __restrict__ ws) {
    const float* Tmp = ws + TMP_OFF;
    const float* bt  = ws + BT_OFF;
    float* Wc = ws + WC_OFF;
    float* bc = ws + BC_OFF;
    int r = blockIdx.x, d = threadIdx.x;
    float acc = 0.f;
    for (int j = 0; j < 128; ++j) acc += Wih[r * 128 + j] * Tmp[j * 128 + d];
    Wc[r * 128 + d] = acc;
    if (d == 0) {
        float s = 0.f;
        for (int j = 0; j < 128; ++j) s += Wih[r * 128 + j] * bt[j];
        bc[r] = s + bih[r];
    }
}

// ---------- main scan: 2 barriers/step ----------
// 512 threads = 8 waves. VALU phases (tail, LN1, LN2): all 8 waves, one batch
// row per wave (r = wave), 2 cols per lane. GEMM phase: waves 0-3 compute
// gi = LN1(x)@Wc^T, waves 4-7 compute gh = h@Whh^T (each wave 6 col-tiles).
__global__ __launch_bounds__(512, 2)
void rppo_scan(const float* __restrict__ x, const float* __restrict__ hxs,
               const float* __restrict__ masks,
               const float* __restrict__ ln1_w, const float* __restrict__ ln1_b,
               const float* __restrict__ Whh, const float* __restrict__ bhh,
               const float* __restrict__ ln2_w, const float* __restrict__ ln2_b,
               const float* __restrict__ ws, float* __restrict__ out)
{
    __shared__ unsigned short fbuf[NB * LDA];   // LN1 out (A of gi)
    __shared__ unsigned short hbuf[NB * LDA];   // masked h (A of gh)
    __shared__ float gibuf[NB * LDG];           // gi(t) + bc
    __shared__ float ghbuf[NB * LDG];           // gh(t) + b_hh
    __shared__ float mbuf[Tt * NB];             // this block's masks

    const int tid  = threadIdx.x;
    const int wave = tid >> 6;
    const int lane = tid & 63;
    const int l16  = lane & 15;
    const int quad = lane >> 4;
    const int arow = l16 & 7;
    const int wsub = wave & 3;
    const bool isP = (wave < 4);
    const int n0   = blockIdx.x * NB;
    const int r    = wave;          // batch row owned in VALU phases
    const int c2   = lane << 1;     // 2 cols per lane

    const float* Wc = ws + WC_OFF;
    const float* bc = ws + BC_OFF;

    // ---- weight fragments: 24 frags = 96 VGPRs per wave, no AGPR overflow ----
    v8s wreg[6][4];
    float brC[6];
    {
        const float* Wm = isP ? Wc : Whh;
        const float* bm = isP ? bc : bhh;
#pragma unroll
        for (int c = 0; c < 6; ++c) {
            int rowc = (6 * wsub + c) * 16 + l16;
            brC[c] = bm[rowc];
#pragma unroll
            for (int kk = 0; kk < 4; ++kk)
                wreg[c][kk] = load_wfrag_bf(Wm, rowc, kk * 32 + quad * 8);
        }
    }

    // masks for this block
    for (int idx = tid; idx < Tt * NB; idx += 512) {
        int t = idx >> 3, b = idx & 7;
        mbuf[idx] = masks[t * Nn + n0 + b];
    }

    v2f ln1w2 = *(const v2f*)(ln1_w + c2);
    v2f ln1b2 = *(const v2f*)(ln1_b + c2);
    v2f ln2w2 = *(const v2f*)(ln2_w + c2);
    v2f ln2b2 = *(const v2f*)(ln2_b + c2);

    // h0 masked by m_0 -> regs + bf16 LDS copy
    v2f h = *(const v2f*)(hxs + (size_t)(n0 + r) * Hh + c2);
    float m0 = masks[n0 + r];
    h[0] *= m0; h[1] *= m0;
    *(unsigned int*)(hbuf + r * LDA + c2) =
        (unsigned int)f2bf(h[0]) | ((unsigned int)f2bf(h[1]) << 16);

    // prefetch x for t=0
    v2f xv = *(const v2f*)(x + (size_t)(n0 + r) * Dd + c2);

    __syncthreads();

    for (int i = 0; i <= Tt; ++i) {
        // ===== seg A: GRU tail(t=i-1) + LN2 + out  |  LN1(t=i) -> fbuf =====
        if (i >= 1) {
            const int t = i - 1;
            const float* gb = gibuf + r * LDG + c2;
            const float* hb = ghbuf + r * LDG + c2;
            v2f ir  = *(const v2f*)(gb);
            v2f iz  = *(const v2f*)(gb + 128);
            v2f inn = *(const v2f*)(gb + 256);
            v2f hr  = *(const v2f*)(hb);
            v2f hz  = *(const v2f*)(hb + 128);
            v2f hn  = *(const v2f*)(hb + 256);
            float hn0, hn1;
            {
                float rg = sigm(ir[0] + hr[0]);
                float z  = sigm(iz[0] + hz[0]);
                float n  = tanh_f(inn[0] + rg * hn[0]);
                hn0 = n + z * (h[0] - n);
            }
            {
                float rg = sigm(ir[1] + hr[1]);
                float z  = sigm(iz[1] + hz[1]);
                float n  = tanh_f(inn[1] + rg * hn[1]);
                hn1 = n + z * (h[1] - n);
            }
            float s2 = hn0 + hn1, ss2 = hn0 * hn0 + hn1 * hn1;
#pragma unroll
            for (int m = 1; m < 64; m <<= 1) {
                s2  += __shfl_xor(s2,  m, 64);
                ss2 += __shfl_xor(ss2, m, 64);
            }
            float mu2 = s2 * (1.f / 128.f);
            float rs2 = __frsqrt_rn(ss2 * (1.f / 128.f) - mu2 * mu2 + 1e-5f);
            v2f o;
            o[0] = (hn0 - mu2) * rs2 * ln2w2[0] + ln2b2[0];
            o[1] = (hn1 - mu2) * rs2 * ln2w2[1] + ln2b2[1];
            *(v2f*)(out + ((size_t)t * Nn + n0 + r) * Hh + c2) = o;

            if (t + 1 < Tt) {
                float mt = mbuf[(t + 1) * NB + r];
                h[0] = hn0 * mt; h[1] = hn1 * mt;
                *(unsigned int*)(hbuf + r * LDA + c2) =
                    (unsigned int)f2bf(h[0]) | ((unsigned int)f2bf(h[1]) << 16);
            } else {
                v2f hf; hf[0] = hn0; hf[1] = hn1;
                *(v2f*)(out + (size_t)Tt * Nn * Hh + (size_t)(n0 + r) * Hh + c2) = hf;
            }
        }
        if (i < Tt) {
            float s = xv[0] + xv[1], ss = xv[0] * xv[0] + xv[1] * xv[1];
#pragma unroll
            for (int m = 1; m < 64; m <<= 1) {
                s  += __shfl_xor(s,  m, 64);
                ss += __shfl_xor(ss, m, 64);
            }
            float mu = s * (1.f / 128.f);
            float rs = __frsqrt_rn(ss * (1.f / 128.f) - mu * mu + 1e-5f);
            float f0 = (xv[0] - mu) * rs * ln1w2[0] + ln1b2[0];
            float f1 = (xv[1] - mu) * rs * ln1w2[1] + ln1b2[1];
            *(unsigned int*)(fbuf + r * LDA + c2) =
                (unsigned int)f2bf(f0) | ((unsigned int)f2bf(f1) << 16);
            if (i + 1 < Tt)
                xv = *(const v2f*)(x + ((size_t)(i + 1) * Nn + n0 + r) * Dd + c2);
        }
        BARRIER();   // B1

        // ===== seg B: P: gi(t)=fbuf@Wc^T -> gibuf | Q: gh(t)=hbuf@Whh^T -> ghbuf =====
        if (i < Tt) {
            const unsigned short* src = isP ? fbuf : hbuf;
            float* dst = isP ? gibuf : ghbuf;
            v8s af[4];
#pragma unroll
            for (int kk = 0; kk < 4; ++kk)
                af[kk] = *(const v8s*)(src + arow * LDA + kk * 32 + quad * 8);
            v4f acc[6];
#pragma unroll
            for (int c = 0; c < 6; ++c) acc[c] = (v4f){0.f, 0.f, 0.f, 0.f};
#pragma unroll
            for (int c = 0; c < 6; ++c)
#pragma unroll
                for (int kk = 0; kk < 4; ++kk)
                    acc[c] = mfma_bf(af[kk], wreg[c][kk], acc[c]);
#pragma unroll
            for (int c = 0; c < 6; ++c) {
                int col = (6 * wsub + c) * 16 + l16;
#pragma unroll
                for (int rr = 0; rr < 4; ++rr) {
                    int row = quad * 4 + rr;
                    if (row < 8) dst[row * LDG + col] = acc[c][rr] + brC[c];
                }
            }
        }
        BARRIER();   // B2
    }
}

extern "C" void kernel_launch(void* const* d_in, const int* in_sizes, int n_in,
                              void* d_out, int out_size, void* d_ws, size_t ws_size,
                              hipStream_t stream) {
    const float* x     = (const float*)d_in[0];
    const float* hxs   = (const float*)d_in[1];
    const float* masks = (const float*)d_in[2];
    const float* ln1w  = (const float*)d_in[3];
    const float* ln1b  = (const float*)d_in[4];
    const float* W1    = (const float*)d_in[5];
    const float* b1    = (const float*)d_in[6];
    const float* W2    = (const float*)d_in[7];
    const float* b2    = (const float*)d_in[8];
    const float* Wih   = (const float*)d_in[9];
    const float* bih   = (const float*)d_in[10];
    const float* Whh   = (const float*)d_in[11];
    const float* bhh   = (const float*)d_in[12];
    const float* ln2w  = (const float*)d_in[13];
    const float* ln2b  = (const float*)d_in[14];
    float* out = (float*)d_out;
    float* ws  = (float*)d_ws;

    // compose MLP weights once (tiny): Tmp=W2@W1, Wc=Wih@Tmp, bc=Wih@(W2@b1+b2)+bih
    hipLaunchKernelGGL(prep_tmp, dim3(128), dim3(128), 0, stream, W1, b1, W2, b2, ws);
    hipLaunchKernelGGL(prep_wc,  dim3(384), dim3(128), 0, stream, Wih, bih, ws);

    hipLaunchKernelGGL(rppo_scan, dim3(Nn / NB), dim3(512), 0, stream,
                       x, hxs, masks, ln1w, ln1b, Whh, bhh, ln2w, ln2b,
                       (const float*)ws, out);
}